// Round 6
// baseline (159.269 us; speedup 1.0000x reference)
//
#include <hip/hip_runtime.h>
#include <math.h>

#define NT 365
#define NT2 368
#define NS 128
#define NG 16
#define NH 8
#define HS 256
#define NSNH (NS * NH)
#define EPSC 1e-6f
#define NHC 46                      // half-chunks of 8 timesteps (368/8)

// Workspace layout (floats):
//   prm:   6*NS*NH @ 0
//   P:     16*NT2*64*4 @ 8192          packed float4 {km, ps, pl, ev}
//   flags: 16*48 u32 @ 1515520         producer->consumer readiness
#define WS_PRM   0
#define WS_P     8192
#define WS_FLAGS (8192 + 16 * NT2 * 64 * 4)

__device__ __forceinline__ float fast_rcp(float v) {
#if __has_builtin(__builtin_amdgcn_rcpf)
    return __builtin_amdgcn_rcpf(v);
#else
    return 1.f / v;
#endif
}

// ---------------- fused kernel ------------------------------------------
// blocks 0..15: scan consumers (wave0 = recurrence, waves 1-3 = loaders+REDC)
// blocks 16..1551: forcing producers (R4 k_main structure, t = t0*8+g)
__global__ __launch_bounds__(256) void k_fused(
    const float* __restrict__ x, const float* __restrict__ xc,
    const float* __restrict__ W_fc, const float* __restrict__ b_fc,
    const float* __restrict__ W_g, const float* __restrict__ b_g,
    const float* __restrict__ W_kin, const float* __restrict__ b_kin,
    const float* __restrict__ W_kout, const float* __restrict__ b_kout,
    float* __restrict__ prm, float4* __restrict__ P,
    unsigned* __restrict__ flags, float* __restrict__ q)
{
    __shared__ __align__(16) char pool[21504];
    int tid = threadIdx.x;
    int wave = tid >> 6, lane = tid & 63;

    if (blockIdx.x >= 16) {
        // ================= PRODUCER =================
        int pb = blockIdx.x - 16;
        int s = pb & 127;
        int t0 = (pb >> 7) * 4 + wave;           // 0..47
        int h = lane >> 3, jg = lane & 7;

        float* us = (float*)pool;                 // 256
        float* ts = us + 256;                     // 256
        float4* wkin_lds = (float4*)(ts + 256);   // 256 float4
        float* wko_lds = (float*)(wkin_lds + 256); // 2080
        float* lds_u = wko_lds + 2080;            // 1152
        float* pgs = lds_u + 1152;                // 48

        // stage W_kin (4KB) and W_kout (padded 8.3KB)
        wkin_lds[tid] = ((const float4*)W_kin)[tid];
#pragma unroll
        for (int i = 0; i < 8; ++i) {
            int idx = tid + 256 * i;
            wko_lds[(idx >> 8) * 260 + (idx & 255)] = W_kout[idx];
        }
        // state row tid for this block's site
        {
            float a = b_fc[tid];
            const float4* wf = (const float4*)(W_fc + tid * NG);
            const float* xr = xc + s * NG;
#pragma unroll
            for (int i = 0; i < 4; ++i) {
                float4 w = wf[i];
                a += xr[4*i] * w.x + xr[4*i+1] * w.y + xr[4*i+2] * w.z + xr[4*i+3] * w.w;
            }
            ts[tid] = tanhf(a);
            us[tid] = a + b_kin[tid];
        }
        __syncthreads();

        // per-wave registers from LDS
        float ust[4]; float4 w4[4];
#pragma unroll
        for (int r = 0; r < 4; ++r) {
            ust[r] = us[lane + 64 * r];
            w4[r]  = wkin_lds[lane + 64 * r];
        }
        float4 wwr[8];
#pragma unroll
        for (int k = 0; k < 8; ++k)
            wwr[k] = *(const float4*)(wko_lds + h * 260 + jg * 32 + 4 * k);
        float bko = b_kout[h];

        // fused param heads for pb 0..127
        if (pb < NS) {
            for (int k = wave; k < 6 * NH; k += 4) {
                float p = 0.f;
#pragma unroll
                for (int r = 0; r < 4; ++r) {
                    int jj = lane + 64 * r;
                    p += ts[jj] * W_g[k * HS + jj];
                }
#pragma unroll
                for (int off = 32; off; off >>= 1) p += __shfl_xor(p, off, 64);
                if (lane == 0) pgs[k] = p + b_g[k];
            }
            __syncthreads();
            if (tid < NH) {
                int hh = tid;
                float gk = expf(pgs[hh]) * 0.01f;
                float gl = expf(pgs[NH + hh]) * 100.f;
                float qb = fmaxf(pgs[2 * NH + hh], 0.f) * 0.1f;
                float m = pgs[3 * NH];
#pragma unroll
                for (int i = 1; i < NH; ++i) m = fmaxf(m, pgs[3 * NH + i]);
                float den = 0.f;
#pragma unroll
                for (int i = 0; i < NH; ++i) den += expf(pgs[3 * NH + i] - m);
                float ga = expf(pgs[3 * NH + hh] - m) / den;
                float gi = fminf(fmaxf(pgs[4 * NH + hh] * (1.f / 6.f) + 0.5f, 0.f), 1.f) * 0.5f;
                float ge = fmaxf(pgs[5 * NH + hh], 0.f);
                int o = s * NH + hh;
                prm[0 * NSNH + o] = gk;
                prm[1 * NSNH + o] = gl;
                prm[2 * NSNH + o] = qb;
                prm[3 * NSNH + o] = ga;
                prm[4 * NSNH + o] = gi;
                prm[5 * NSNH + o] = ge;
            }
        }

        // forcing loop: 8 CONTIGUOUS time steps t = t0*8 + g
        float* uw = lds_u + wave * 288;
        int ubase = lane + 4 * (lane >> 5);
        const float4* uuP = (const float4*)(uw + jg * 36);
        int sblk = s >> 3, srem = (s & 7) * 8;

#pragma unroll
        for (int g = 0; g < 8; ++g) {
            int t = t0 * 8 + g;                  // 0..383
            if (t >= NT2) continue;              // t0 46,47: nothing to write
            if (t >= NT) {                       // zero-pad 365..367
                if (jg == 0)
                    P[(sblk * NT2 + t) * 64 + srem + h] = make_float4(0.f, 0.f, 0.f, 0.f);
                continue;
            }
            const float2* xr2 = (const float2*)(x + (size_t)(t * NS + s) * 6);
            float2 a01 = xr2[0], a23 = xr2[1], a45 = xr2[2];
            float prcp = a01.x, ev = a01.y;
            float f0 = a23.x, f1 = a23.y, f2 = a45.x, f3 = a45.y;
#pragma unroll
            for (int r = 0; r < 4; ++r) {
                float e = __expf(2.f * (ust[r] + f0 * w4[r].x + f1 * w4[r].y +
                                        f2 * w4[r].z + f3 * w4[r].w));
                uw[ubase + 72 * r] = 1.f - 2.f * fast_rcp(e + 1.f);
            }
            float r_ = (f0 + f1) / fmaxf(f1 - f0, EPSC);
            r_ = fminf(fmaxf(r_, -1.f), 1.f);
            float vf = acosf(r_) * 0.31830988618379067f;   // 1/pi
            if (f0 >= 0.f) vf = 0.f;
            if (f1 <= 0.f) vf = 1.f;
            float psv = prcp * vf;
            float plv = prcp * (1.f - vf);
            float acc = 0.f;
#pragma unroll
            for (int k = 0; k < 8; ++k) {
                float4 a = uuP[k], b = wwr[k];
                acc += a.x * b.x + a.y * b.y + a.z * b.z + a.w * b.w;
            }
            acc += __shfl_xor(acc, 1, 64);
            acc += __shfl_xor(acc, 2, 64);
            acc += __shfl_xor(acc, 4, 64);
            if (jg == 0)
                P[(sblk * NT2 + t) * 64 + srem + h] =
                    make_float4(__expf(acc + bko), psv, plv, ev);
        }

        // release-signal: this wave's (site, t0) half-chunk is complete.
        // s_waitcnt vmcnt(0) before the atomic covers the whole wave's stores.
        if (lane == 0)
            __hip_atomic_fetch_add(flags + ((s >> 3) * 48 + t0), 1u,
                                   __ATOMIC_RELEASE, __HIP_MEMORY_SCOPE_AGENT);
        return;
    }

    // ================= CONSUMER (scan) =================
    int b = blockIdx.x;                          // 0..15
    float4* ring = (float4*)pool;                // [2][8][64] float4 = 16KB
    float*  outb = (float*)(ring + 1024);        // [2][576]
    const float4* Pb = P + (size_t)b * (NT2 * 64);
    unsigned* flg = flags + b * 48;

#define WAITF(hc) { \
    while (__hip_atomic_load(flg + (hc), __ATOMIC_ACQUIRE, __HIP_MEMORY_SCOPE_AGENT) < 8u) \
        __builtin_amdgcn_s_sleep(8); }

    if (wave == 0) {
        // recurrence wave: one lane per (s,h)
        WAITF(0);
        int gofs = b * 64 + lane;
        float gk = prm[0 * NSNH + gofs];
        float gl = prm[1 * NSNH + gofs];
        float qb = prm[2 * NSNH + gofs];
        float gi = prm[4 * NSNH + gofs];
        float ge = prm[5 * NSNH + gofs];
        float c1 = 1.f - gk, nqb = -qb, nge = -ge;
        float S = 0.f, sf = 0.f;
        __syncthreads();                          // prologue barrier
        for (int hc = 0; hc < NHC; ++hc) {
            const float4* rs = ring + (hc & 1) * 512;
            float* ob = outb + (hc & 1) * 576;
#pragma unroll
            for (int c = 0; c < 8; ++c) {
                float4 a = rs[c * 64 + lane];
                float sf1 = sf + a.y;
                float melt = fminf(sf1, a.x);
                sf = sf1 - melt;
                float Sw = S + fmaf(a.z, gi, melt);
                float t2v = fmaf(a.w, nge, Sw);
                float S1 = fmaxf(t2v, 0.f);
                float S2 = __builtin_amdgcn_fmed3f(t2v, 0.f, gl);
                float Sn = fmaxf(fmaf(S2, c1, nqb), 0.f);
                S = Sn;
                ob[lane * 9 + c] = S1 - Sn;
            }
            __syncthreads();
        }
    } else {
        // loader + reduce waves
        int k = tid - 64;                         // 0..191
        bool redr = (wave == 1);
        int cq = lane >> 3, sq = lane & 7;        // REDC task (c, site)
        float gar[8];
        WAITF(0);
        if (redr)
#pragma unroll
            for (int hh = 0; hh < 8; ++hh)
                gar[hh] = prm[3 * NSNH + (b * 8 + sq) * 8 + hh];
        for (int idx = k; idx < 512; idx += 192) ring[idx] = Pb[idx];
        __syncthreads();                          // prologue barrier
        for (int hc = 0; hc < NHC; ++hc) {
            if (hc >= 1 && redr) {
                float* ob = outb + ((hc - 1) & 1) * 576;
                float sum = 0.f;
#pragma unroll
                for (int hh = 0; hh < 8; ++hh)
                    sum = fmaf(gar[hh], ob[(sq * 8 + hh) * 9 + cq], sum);
                int t = (hc - 1) * 8 + cq;
                if (t < NT) q[t * NS + b * 8 + sq] = sum;
            }
            if (hc + 1 < NHC) {
                WAITF(hc + 1);
                float4* rd = ring + ((hc + 1) & 1) * 512;
                const float4* gp = Pb + (hc + 1) * 512;
                for (int idx = k; idx < 512; idx += 192) rd[idx] = gp[idx];
            }
            __syncthreads();
        }
        if (redr) {                               // REDC for last half-chunk
            float* ob = outb + ((NHC - 1) & 1) * 576;
            float sum = 0.f;
#pragma unroll
            for (int hh = 0; hh < 8; ++hh)
                sum = fmaf(gar[hh], ob[(sq * 8 + hh) * 9 + cq], sum);
            int t = (NHC - 1) * 8 + cq;
            if (t < NT) q[t * NS + b * 8 + sq] = sum;
        }
    }
#undef WAITF
}

extern "C" void kernel_launch(void* const* d_in, const int* in_sizes, int n_in,
                              void* d_out, int out_size, void* d_ws, size_t ws_size,
                              hipStream_t stream)
{
    const float* x      = (const float*)d_in[0];
    const float* xc     = (const float*)d_in[1];
    const float* W_fc   = (const float*)d_in[2];
    const float* b_fc   = (const float*)d_in[3];
    const float* W_g    = (const float*)d_in[4];
    const float* b_g    = (const float*)d_in[5];
    const float* W_kin  = (const float*)d_in[6];
    const float* b_kin  = (const float*)d_in[7];
    const float* W_kout = (const float*)d_in[8];
    const float* b_kout = (const float*)d_in[9];
    float* q = (float*)d_out;

    float* ws       = (float*)d_ws;
    float* prm      = ws + WS_PRM;
    float4* P       = (float4*)(ws + WS_P);
    unsigned* flags = (unsigned*)(ws + WS_FLAGS);

    // zero the 3KB flag array each call (capturable memset node)
    hipMemsetAsync(flags, 0, 16 * 48 * sizeof(unsigned), stream);

    hipLaunchKernelGGL(k_fused, dim3(16 + 1536), dim3(256), 0, stream,
                       x, xc, W_fc, b_fc, W_g, b_g, W_kin, b_kin,
                       W_kout, b_kout, prm, P, flags, q);
}

// Round 7
// 66.189 us; speedup vs baseline: 2.4063x; 2.4063x over previous
//
#include <hip/hip_runtime.h>
#include <math.h>

#define NT 365
#define NT2 368
#define NS 128
#define NG 16
#define NH 8
#define HS 256
#define NSNH (NS * NH)
#define EPSC 1e-6f
#define CH 16                       // timesteps per scan chunk
#define NCH 23                      // chunks (368/16)

// Workspace layout (floats):
//   prm: 6*NS*NH @ 0      order: gk, gl, qb, ga, gi, ge
//   P:   16*NT2*64*4 @ 8192   packed float4 {km, ps, c=pl*gi-ev*ge, 0}
#define WS_PRM 0
#define WS_P   8192

__device__ __forceinline__ float fast_rcp(float v) {
#if __has_builtin(__builtin_amdgcn_rcpf)
    return __builtin_amdgcn_rcpf(v);
#else
    return 1.f / v;
#endif
}

// ---------------- K_main: forcing (+ fused per-site param heads) ----------
// 1536 blocks x 256. Each BLOCK owns one site s = blockIdx&127 (R4 structure).
// All blocks compute the 48 pg head rows (need gi/ge for the P payload);
// blocks 0..127 additionally store prm[site].
__global__ __launch_bounds__(256) void k_main(
    const float* __restrict__ x, const float* __restrict__ xc,
    const float* __restrict__ W_fc, const float* __restrict__ b_fc,
    const float* __restrict__ W_g, const float* __restrict__ b_g,
    const float* __restrict__ W_kin, const float* __restrict__ b_kin,
    const float* __restrict__ W_kout, const float* __restrict__ b_kout,
    float* __restrict__ prm, float4* __restrict__ P)
{
    __shared__ float us[HS];                     // state + b_kin
    __shared__ float ts[HS];                     // tanh(state)
    __shared__ __align__(16) float4 wkin_lds[HS];
    __shared__ float wko_lds[8 * 260];           // padded rows
    __shared__ __align__(16) float lds_u[4 * 288];
    __shared__ float pgs[6 * NH];
    __shared__ float gie[NH], gee[NH];

    int tid = threadIdx.x;
    int wave = tid >> 6, lane = tid & 63;
    int s = blockIdx.x & 127;
    int t0 = (blockIdx.x >> 7) * 4 + wave;       // 0..47
    int h = lane >> 3, jg = lane & 7;

    // stage W_kin (4KB) and W_kout (padded 8.3KB)
    wkin_lds[tid] = ((const float4*)W_kin)[tid];
#pragma unroll
    for (int i = 0; i < 8; ++i) {
        int idx = tid + 256 * i;
        wko_lds[(idx >> 8) * 260 + (idx & 255)] = W_kout[idx];
    }
    // state row tid for this block's site (one W_fc pass per block)
    {
        float a = b_fc[tid];
        const float4* wf = (const float4*)(W_fc + tid * NG);
        const float* xr = xc + s * NG;
#pragma unroll
        for (int i = 0; i < 4; ++i) {
            float4 w = wf[i];
            a += xr[4*i] * w.x + xr[4*i+1] * w.y + xr[4*i+2] * w.z + xr[4*i+3] * w.w;
        }
        ts[tid] = tanhf(a);
        us[tid] = a + b_kin[tid];
    }
    __syncthreads();

    // per-wave registers from LDS (read once, reused over 8 slots)
    float ust[4]; float4 w4[4];
#pragma unroll
    for (int r = 0; r < 4; ++r) {
        ust[r] = us[lane + 64 * r];
        w4[r]  = wkin_lds[lane + 64 * r];
    }
    float4 wwr[8];
#pragma unroll
    for (int k = 0; k < 8; ++k)
        wwr[k] = *(const float4*)(wko_lds + h * 260 + jg * 32 + 4 * k);
    float bko = b_kout[h];

    // pg head rows (ALL blocks; needed for gi/ge in the P payload)
    for (int k = wave; k < 6 * NH; k += 4) {
        float p = 0.f;
#pragma unroll
        for (int r = 0; r < 4; ++r) {
            int jj = lane + 64 * r;
            p += ts[jj] * W_g[k * HS + jj];
        }
#pragma unroll
        for (int off = 32; off; off >>= 1) p += __shfl_xor(p, off, 64);
        if (lane == 0) pgs[k] = p + b_g[k];
    }
    __syncthreads();

    if (tid < NH) {
        gie[tid] = fminf(fmaxf(pgs[4 * NH + tid] * (1.f / 6.f) + 0.5f, 0.f), 1.f) * 0.5f;
        gee[tid] = fmaxf(pgs[5 * NH + tid], 0.f);
    }
    if (blockIdx.x < NS && tid < NH) {
        int hh = tid;
        float gk = expf(pgs[hh]) * 0.01f;
        float gl = expf(pgs[NH + hh]) * 100.f;
        float qb = fmaxf(pgs[2 * NH + hh], 0.f) * 0.1f;
        float m = pgs[3 * NH];
#pragma unroll
        for (int i = 1; i < NH; ++i) m = fmaxf(m, pgs[3 * NH + i]);
        float den = 0.f;
#pragma unroll
        for (int i = 0; i < NH; ++i) den += expf(pgs[3 * NH + i] - m);
        float ga = expf(pgs[3 * NH + hh] - m) / den;
        float gi = fminf(fmaxf(pgs[4 * NH + hh] * (1.f / 6.f) + 0.5f, 0.f), 1.f) * 0.5f;
        float ge = fmaxf(pgs[5 * NH + hh], 0.f);
        int o = s * NH + hh;
        prm[0 * NSNH + o] = gk;
        prm[1 * NSNH + o] = gl;
        prm[2 * NSNH + o] = qb;
        prm[3 * NSNH + o] = ga;
        prm[4 * NSNH + o] = gi;
        prm[5 * NSNH + o] = ge;
    }
    __syncthreads();

    float gih = gie[h], geh = gee[h];

    // main forcing loop: 8 time slots per wave (R4 structure)
    float* uw = lds_u + wave * 288;
    int ubase = lane + 4 * (lane >> 5);          // u[j] at j + 4*(j>>5)
    const float4* uuP = (const float4*)(uw + jg * 36);
    int sblk = s >> 3, srem = (s & 7) * 8;

#pragma unroll
    for (int g = 0; g < 8; ++g) {
        int t = t0 + 48 * g;                     // 0..383
        if (t >= NT) {                           // wave-uniform tail
            if (t < NT2 && jg == 0)
                P[(sblk * NT2 + t) * 64 + srem + h] = make_float4(0.f, 0.f, 0.f, 0.f);
            continue;
        }
        const float2* xr2 = (const float2*)(x + (size_t)(t * NS + s) * 6);
        float2 a01 = xr2[0], a23 = xr2[1], a45 = xr2[2];
        float prcp = a01.x, ev = a01.y;
        float f0 = a23.x, f1 = a23.y, f2 = a45.x, f3 = a45.y;
#pragma unroll
        for (int r = 0; r < 4; ++r) {
            float e = __expf(2.f * (ust[r] + f0 * w4[r].x + f1 * w4[r].y +
                                    f2 * w4[r].z + f3 * w4[r].w));
            uw[ubase + 72 * r] = 1.f - 2.f * fast_rcp(e + 1.f);
        }
        float r_ = (f0 + f1) / fmaxf(f1 - f0, EPSC);
        r_ = fminf(fmaxf(r_, -1.f), 1.f);
        float vf = acosf(r_) * 0.31830988618379067f;   // 1/pi
        if (f0 >= 0.f) vf = 0.f;
        if (f1 <= 0.f) vf = 1.f;
        float psv = prcp * vf;
        float plv = prcp * (1.f - vf);
        float acc = 0.f;
#pragma unroll
        for (int k = 0; k < 8; ++k) {
            float4 a = uuP[k], b = wwr[k];
            acc += a.x * b.x + a.y * b.y + a.z * b.z + a.w * b.w;
        }
        acc += __shfl_xor(acc, 1, 64);
        acc += __shfl_xor(acc, 2, 64);
        acc += __shfl_xor(acc, 4, 64);
        if (jg == 0)
            P[(sblk * NT2 + t) * 64 + srem + h] =
                make_float4(__expf(acc + bko), psv, plv * gih - ev * geh, 0.f);
    }
}

// ---------------- K_scan: wave-specialized collapsed scan -----------------
// 16 blocks x 256 (4 waves). wave0 = pure recurrence from a 3-chunk LDS
// ring; waves 1-3 = reg-staged loaders; waves 2-3 also do the ga-reduce
// and q stores one chunk behind. One barrier per 16-step chunk.
__global__ __launch_bounds__(256, 1) void k_scan(
    const float4* __restrict__ P, const float* __restrict__ prm,
    float* __restrict__ q)
{
    __shared__ __align__(16) float4 ring[3][CH][64];   // 48 KB
    __shared__ float outb[2][CH * 72];                 // 9 KB

    int tid = threadIdx.x, wave = tid >> 6, lane = tid & 63;
    int blk = blockIdx.x;
    const float4* Pb = P + (size_t)blk * (NT2 * 64);

    if (wave == 0) {
        int gofs = blk * 64 + lane;
        float gk = prm[0 * NSNH + gofs];
        float gl = prm[1 * NSNH + gofs];
        float qb = prm[2 * NSNH + gofs];
        float c1 = 1.f - gk, nqb = -qb;
        float S = 0.f, sf = 0.f;
        int obase = (lane >> 3) * 9 + (lane & 7);
        __syncthreads();                           // prologue
        for (int c = 0; c < NCH; ++c) {
            const float4* rs = &ring[c % 3][0][lane];
            float* ob = &outb[c & 1][obase];
#pragma unroll
            for (int st = 0; st < CH; ++st) {
                float4 a = rs[st * 64];
                float sf1 = sf + a.y;
                float melt = fminf(sf1, a.x);
                sf = sf1 - melt;
                float t2v = (S + a.z) + melt;      // S+c_t overlaps melt chain
                float S1 = fmaxf(t2v, 0.f);
                float S2 = __builtin_amdgcn_fmed3f(t2v, 0.f, gl);
                float Sn = fmaxf(fmaf(S2, c1, nqb), 0.f);
                S = Sn;
                ob[st * 72] = S1 - Sn;
            }
            __syncthreads();
        }
        return;
    }

    // loader (+reduce) waves
    int w = wave - 1;                              // 0..2
    int nrows = (w == 0) ? 6 : 5;
    float4 regs[6];
    int sq = lane & 7;
    float gar[8];
    if (w >= 1) {
#pragma unroll
        for (int hh = 0; hh < 8; ++hh)
            gar[hh] = prm[3 * NSNH + (blk * 8 + sq) * 8 + hh];
    }
    // prologue: chunks 0,1 -> ring; chunk 2 -> regs
#pragma unroll
    for (int ck = 0; ck < 2; ++ck) {
        for (int i = 0; i < 6; ++i) {
            int row = w + 3 * i;
            if (i < nrows) regs[i] = Pb[(ck * CH + row) * 64 + lane];
        }
        for (int i = 0; i < 6; ++i) {
            int row = w + 3 * i;
            if (i < nrows) ring[ck][row][lane] = regs[i];
        }
    }
    for (int i = 0; i < 6; ++i) {
        int row = w + 3 * i;
        if (i < nrows) regs[i] = Pb[(2 * CH + row) * 64 + lane];
    }
    __syncthreads();                               // prologue

    for (int c = 0; c < NCH; ++c) {
        if (c + 2 < NCH) {
            int slot = (c + 2) % 3;
            for (int i = 0; i < 6; ++i) {
                int row = w + 3 * i;
                if (i < nrows) ring[slot][row][lane] = regs[i];
            }
            if (c + 3 < NCH) {
                for (int i = 0; i < 6; ++i) {
                    int row = w + 3 * i;
                    if (i < nrows) regs[i] = Pb[((c + 3) * CH + row) * 64 + lane];
                }
            }
        }
        if (w >= 1 && c >= 1) {                    // reduce chunk c-1
            int cq = (w - 1) * 8 + (lane >> 3);    // 0..15
            const float* ob = &outb[(c - 1) & 1][cq * 72 + sq * 9];
            float sum = 0.f;
#pragma unroll
            for (int hh = 0; hh < 8; ++hh) sum = fmaf(gar[hh], ob[hh], sum);
            int t = (c - 1) * CH + cq;
            if (t < NT) q[t * NS + blk * 8 + sq] = sum;
        }
        __syncthreads();
    }
    if (w >= 1) {                                  // reduce last chunk
        int cq = (w - 1) * 8 + (lane >> 3);
        const float* ob = &outb[(NCH - 1) & 1][cq * 72 + sq * 9];
        float sum = 0.f;
#pragma unroll
        for (int hh = 0; hh < 8; ++hh) sum = fmaf(gar[hh], ob[hh], sum);
        int t = (NCH - 1) * CH + cq;
        if (t < NT) q[t * NS + blk * 8 + sq] = sum;
    }
}

extern "C" void kernel_launch(void* const* d_in, const int* in_sizes, int n_in,
                              void* d_out, int out_size, void* d_ws, size_t ws_size,
                              hipStream_t stream)
{
    const float* x      = (const float*)d_in[0];
    const float* xc     = (const float*)d_in[1];
    const float* W_fc   = (const float*)d_in[2];
    const float* b_fc   = (const float*)d_in[3];
    const float* W_g    = (const float*)d_in[4];
    const float* b_g    = (const float*)d_in[5];
    const float* W_kin  = (const float*)d_in[6];
    const float* b_kin  = (const float*)d_in[7];
    const float* W_kout = (const float*)d_in[8];
    const float* b_kout = (const float*)d_in[9];
    float* q = (float*)d_out;

    float* ws  = (float*)d_ws;
    float* prm = ws + WS_PRM;
    float4* P  = (float4*)(ws + WS_P);

    hipLaunchKernelGGL(k_main, dim3(1536), dim3(256), 0, stream,
                       x, xc, W_fc, b_fc, W_g, b_g, W_kin, b_kin,
                       W_kout, b_kout, prm, P);

    hipLaunchKernelGGL(k_scan, dim3(16), dim3(256), 0, stream,
                       P, prm, q);
}

// Round 8
// 38.451 us; speedup vs baseline: 4.1422x; 1.7214x over previous
//
#include <hip/hip_runtime.h>
#include <math.h>

#define NT 365
#define NT2 368
#define NS 128
#define NG 16
#define NH 8
#define HS 256
#define NSNH (NS * NH)
#define EPSC 1e-6f
#define TSTRIDE 96                  // floats per (site-group, t): 64 km + 8*float4 aux

// Workspace layout (floats):
//   prm: 6*NS*NH @ 0      order: gk, gl, qb, ga, gi, ge
//   Pf:  16*NT2*96 @ 8192     [64 km][8 x float4 {ps,pl,ev,0}] per (blk,t)
#define WS_PRM 0
#define WS_P   8192

__device__ __forceinline__ float fast_rcp(float v) {
#if __has_builtin(__builtin_amdgcn_rcpf)
    return __builtin_amdgcn_rcpf(v);
#else
    return 1.f / v;
#endif
}
__device__ __forceinline__ float fast_tanh(float xv) {
    float e = __expf(2.f * xv);   // overflow -> inf -> rcp -> 0 -> tanh=1 (correct limit)
    return 1.f - 2.f * fast_rcp(e + 1.f);
}

// ---------------- K_main: forcing (+ fused per-site param heads) ----------
// R4 structure verbatim; only the P write format changed (96-float stride).
__global__ __launch_bounds__(256) void k_main(
    const float* __restrict__ x, const float* __restrict__ xc,
    const float* __restrict__ W_fc, const float* __restrict__ b_fc,
    const float* __restrict__ W_g, const float* __restrict__ b_g,
    const float* __restrict__ W_kin, const float* __restrict__ b_kin,
    const float* __restrict__ W_kout, const float* __restrict__ b_kout,
    float* __restrict__ prm, float* __restrict__ Pf)
{
    __shared__ float us[HS];                     // state + b_kin
    __shared__ float ts[HS];                     // tanh(state)
    __shared__ __align__(16) float4 wkin_lds[HS];
    __shared__ float wko_lds[8 * 260];           // padded rows
    __shared__ __align__(16) float lds_u[4 * 288];
    __shared__ float pgs[6 * NH];

    int tid = threadIdx.x;
    int wave = tid >> 6, lane = tid & 63;
    int s = blockIdx.x & 127;
    int t0 = (blockIdx.x >> 7) * 4 + wave;       // 0..47
    int h = lane >> 3, jg = lane & 7;

    // stage W_kin (4KB) and W_kout (padded 8.3KB)
    wkin_lds[tid] = ((const float4*)W_kin)[tid];
#pragma unroll
    for (int i = 0; i < 8; ++i) {
        int idx = tid + 256 * i;
        wko_lds[(idx >> 8) * 260 + (idx & 255)] = W_kout[idx];
    }
    // state row tid for this block's site (one W_fc pass per block)
    {
        float a = b_fc[tid];
        const float4* wf = (const float4*)(W_fc + tid * NG);
        const float* xr = xc + s * NG;
#pragma unroll
        for (int i = 0; i < 4; ++i) {
            float4 w = wf[i];
            a += xr[4*i] * w.x + xr[4*i+1] * w.y + xr[4*i+2] * w.z + xr[4*i+3] * w.w;
        }
        ts[tid] = tanhf(a);
        us[tid] = a + b_kin[tid];
    }
    __syncthreads();

    // per-wave registers from LDS (read once, reused over 8 slots)
    float ust[4]; float4 w4[4];
#pragma unroll
    for (int r = 0; r < 4; ++r) {
        ust[r] = us[lane + 64 * r];
        w4[r]  = wkin_lds[lane + 64 * r];
    }
    float4 wwr[8];
#pragma unroll
    for (int k = 0; k < 8; ++k)
        wwr[k] = *(const float4*)(wko_lds + h * 260 + jg * 32 + 4 * k);
    float bko = b_kout[h];

    // fused param heads for blocks 0..127 (site == blockIdx)
    if (blockIdx.x < NS) {
        for (int k = wave; k < 6 * NH; k += 4) {
            float p = 0.f;
#pragma unroll
            for (int r = 0; r < 4; ++r) {
                int jj = lane + 64 * r;
                p += ts[jj] * W_g[k * HS + jj];
            }
#pragma unroll
            for (int off = 32; off; off >>= 1) p += __shfl_xor(p, off, 64);
            if (lane == 0) pgs[k] = p + b_g[k];
        }
        __syncthreads();
        if (tid < NH) {
            int hh = tid;
            float gk = expf(pgs[hh]) * 0.01f;
            float gl = expf(pgs[NH + hh]) * 100.f;
            float qb = fmaxf(pgs[2 * NH + hh], 0.f) * 0.1f;
            float m = pgs[3 * NH];
#pragma unroll
            for (int i = 1; i < NH; ++i) m = fmaxf(m, pgs[3 * NH + i]);
            float den = 0.f;
#pragma unroll
            for (int i = 0; i < NH; ++i) den += expf(pgs[3 * NH + i] - m);
            float ga = expf(pgs[3 * NH + hh] - m) / den;
            float gi = fminf(fmaxf(pgs[4 * NH + hh] * (1.f / 6.f) + 0.5f, 0.f), 1.f) * 0.5f;
            float ge = fmaxf(pgs[5 * NH + hh], 0.f);
            int o = s * NH + hh;
            prm[0 * NSNH + o] = gk;
            prm[1 * NSNH + o] = gl;
            prm[2 * NSNH + o] = qb;
            prm[3 * NSNH + o] = ga;
            prm[4 * NSNH + o] = gi;
            prm[5 * NSNH + o] = ge;
        }
    }

    // main forcing loop: 8 time slots per wave (R4 structure)
    float* uw = lds_u + wave * 288;
    int ubase = lane + 4 * (lane >> 5);          // u[j] at j + 4*(j>>5)
    const float4* uuP = (const float4*)(uw + jg * 36);
    int sblk = s >> 3, srem = (s & 7) * 8;

#pragma unroll
    for (int g = 0; g < 8; ++g) {
        int t = t0 + 48 * g;                     // 0..383
        float* Pt = Pf + (size_t)(sblk * NT2 + t) * TSTRIDE;
        if (t >= NT) {                           // wave-uniform tail
            if (t < NT2) {
                if (jg == 0) Pt[srem + h] = 0.f;
                if (lane == 0)
                    ((float4*)(Pt + 64))[s & 7] = make_float4(0.f, 0.f, 0.f, 0.f);
            }
            continue;
        }
        const float2* xr2 = (const float2*)(x + (size_t)(t * NS + s) * 6);
        float2 a01 = xr2[0], a23 = xr2[1], a45 = xr2[2];
        float prcp = a01.x, ev = a01.y;
        float f0 = a23.x, f1 = a23.y, f2 = a45.x, f3 = a45.y;
#pragma unroll
        for (int r = 0; r < 4; ++r) {
            float uval = fast_tanh(ust[r] + f0 * w4[r].x + f1 * w4[r].y +
                                   f2 * w4[r].z + f3 * w4[r].w);
            uw[ubase + 72 * r] = uval;
        }
        float r_ = (f0 + f1) / fmaxf(f1 - f0, EPSC);
        r_ = fminf(fmaxf(r_, -1.f), 1.f);
        float vf = acosf(r_) * 0.31830988618379067f;   // 1/pi
        if (f0 >= 0.f) vf = 0.f;
        if (f1 <= 0.f) vf = 1.f;
        float psv = prcp * vf;
        float plv = prcp * (1.f - vf);
        float acc = 0.f;
#pragma unroll
        for (int k = 0; k < 8; ++k) {
            float4 a = uuP[k], b = wwr[k];
            acc += a.x * b.x + a.y * b.y + a.z * b.z + a.w * b.w;
        }
        acc += __shfl_xor(acc, 1, 64);
        acc += __shfl_xor(acc, 2, 64);
        acc += __shfl_xor(acc, 4, 64);
        if (jg == 0) Pt[srem + h] = __expf(acc + bko);
        if (lane == 0)
            ((float4*)(Pt + 64))[s & 7] = make_float4(psv, plv, ev, 0.f);
    }
}

// ---------------- K_scan: R4 structure, compact-P loads -------------------
__global__ __launch_bounds__(64, 1) void k_scan(
    const float* __restrict__ Pf, const float* __restrict__ prm,
    float* __restrict__ q)
{
    int lane = threadIdx.x;
    int blk = blockIdx.x;               // 0..15
    int sbase = blk * 8;
    int gofs = blk * 64 + lane;         // s*NH + h
    int sl = lane >> 3;                 // local site

    float gk = prm[0 * NSNH + gofs];
    float gl = prm[1 * NSNH + gofs];
    float qb = prm[2 * NSNH + gofs];
    float gi = prm[4 * NSNH + gofs];
    float ge = prm[5 * NSNH + gofs];
    float c1 = 1.f - gk, nqb = -qb, nge = -ge;
    int ss0 = lane & 7;
    float gar[8];                        // ga[site ss0][h] for the REDC role
#pragma unroll
    for (int hh = 0; hh < 8; ++hh)
        gar[hh] = prm[3 * NSNH + (sbase + ss0) * 8 + hh];

    __shared__ float out_lds[64 * 17];
    float S = 0.f, sf = 0.f;
    const float* Pb = Pf + (size_t)blk * (NT2 * TSTRIDE);

    float kmA[16], kmB[16], kmC[16];
    float4 axA[16], axB[16], axC[16];

#define LOADC(ci, KM, AX) { const float* p_ = Pb + (ci) * (16 * TSTRIDE); \
    _Pragma("unroll") for (int c = 0; c < 16; ++c) { \
        KM[c] = p_[c * TSTRIDE + lane]; \
        AX[c] = ((const float4*)(p_ + c * TSTRIDE + 64))[sl]; \
    } }

#define WORKC(KM, AX, tb) { \
    _Pragma("unroll") for (int c = 0; c < 16; ++c) { \
        float4 a = AX[c]; \
        float sf1 = sf + a.x; \
        float melt = fminf(sf1, KM[c]); \
        sf = sf1 - melt; \
        float Sw = S + fmaf(a.y, gi, melt); \
        float t2v = fmaf(a.z, nge, Sw); \
        float S1 = fmaxf(t2v, 0.f); \
        float S2 = __builtin_amdgcn_fmed3f(t2v, 0.f, gl); \
        float Sn = fmaxf(fmaf(S2, c1, nqb), 0.f); \
        S = Sn; \
        out_lds[lane * 17 + c] = S1 - Sn; \
    } \
    _Pragma("unroll") for (int it = 0; it < 2; ++it) { \
        int idx = it * 64 + lane; int c = idx >> 3; \
        float sum = 0.f; \
        _Pragma("unroll") for (int hh = 0; hh < 8; ++hh) \
            sum = fmaf(gar[hh], out_lds[(ss0 * 8 + hh) * 17 + c], sum); \
        int t = (tb) + c; \
        if (t < NT) q[t * NS + sbase + ss0] = sum; \
    } }

    LOADC(0, kmA, axA); LOADC(1, kmB, axB);
    for (int k = 0; k < 7; ++k) {
        int c3 = 3 * k;
        LOADC(c3 + 2, kmC, axC); WORKC(kmA, axA, c3 * 16);
        LOADC(c3 + 3, kmA, axA); WORKC(kmB, axB, (c3 + 1) * 16);
        LOADC(c3 + 4, kmB, axB); WORKC(kmC, axC, (c3 + 2) * 16);
    }
    WORKC(kmA, axA, 21 * 16); WORKC(kmB, axB, 22 * 16);
#undef LOADC
#undef WORKC
}

extern "C" void kernel_launch(void* const* d_in, const int* in_sizes, int n_in,
                              void* d_out, int out_size, void* d_ws, size_t ws_size,
                              hipStream_t stream)
{
    const float* x      = (const float*)d_in[0];
    const float* xc     = (const float*)d_in[1];
    const float* W_fc   = (const float*)d_in[2];
    const float* b_fc   = (const float*)d_in[3];
    const float* W_g    = (const float*)d_in[4];
    const float* b_g    = (const float*)d_in[5];
    const float* W_kin  = (const float*)d_in[6];
    const float* b_kin  = (const float*)d_in[7];
    const float* W_kout = (const float*)d_in[8];
    const float* b_kout = (const float*)d_in[9];
    float* q = (float*)d_out;

    float* ws  = (float*)d_ws;
    float* prm = ws + WS_PRM;
    float* Pf  = ws + WS_P;

    hipLaunchKernelGGL(k_main, dim3(1536), dim3(256), 0, stream,
                       x, xc, W_fc, b_fc, W_g, b_g, W_kin, b_kin,
                       W_kout, b_kout, prm, Pf);

    hipLaunchKernelGGL(k_scan, dim3(16), dim3(64), 0, stream,
                       Pf, prm, q);
}